// Round 3
// baseline (404.781 us; speedup 1.0000x reference)
//
#include <hip/hip_runtime.h>

#define DT 0.01f

// Redundant-compute decomposition: FOUR threads per batch element, all four
// running the identical 50-step scan in registers (compute is ~2us/wave --
// duplicating it is free). Each thread stores one float4 subslot of its
// element's 64B per-group output chunk, so a wave's single store instruction
// covers 16 elements x 4 lanes = 16 FULL 64B sectors -- exactly the sector
// pattern the previous version bought with an LDS transpose, now with ZERO
// LDS ops, zero lgkmcnt waits, and a per-group body of just
// compute -> select -> 1 store.
// Grid grows 512 -> 2048 blocks (8192 waves): residency becomes VGPR-capped
// (~12 waves/CU) instead of grid-capped (8 waves/CU).
// Duplicate-address action loads from 4 adjacent lanes coalesce in the TA
// (16 unique sectors per instruction) -> HBM read traffic unchanged.
__global__ __launch_bounds__(256) void hybrid_sim_kernel(
    const float* __restrict__ fs,
    const float* __restrict__ actions,
    const float* __restrict__ pm,  const float* __restrict__ pCaf,
    const float* __restrict__ pCar, const float* __restrict__ plf,
    const float* __restrict__ plr, const float* __restrict__ pIz,
    float* __restrict__ out)
{
    const int tid = threadIdx.x;
    const int sub = tid & 3;                     // float4 subslot within element
    const int e   = blockIdx.x * 64 + (tid >> 2); // element index (64 per block)

    // initial state: full_states[e, 0, 0:8]  (4 adjacent lanes read the same
    // 32B -- dedup'd by the coalescer)
    const float4* fsp = (const float4*)(fs + (size_t)e * 8);
    float4 f0 = fsp[0];
    float4 f1 = fsp[1];
    float s0=f0.x, s1=f0.y, s2=f0.z, s3=f0.w, s4=f1.x, s5=f1.y, u0=f1.z, u1=f1.w;

    // wave-uniform coefficients
    float m=*pm, Caf=*pCaf, Car=*pCar, lf=*plf, lr=*plr, Iz=*pIz;
    float k1  = 2.f*(Caf+Car)/m;
    float k2  = 2.f*(Caf*lf-Car*lr)/m;
    float k3  = 2.f*(lf*Caf-lr*Car)/Iz;
    float k4  = 2.f*(lf*lf*Caf+lr*lr*Car)/Iz;
    float b31 = 2.f*Caf/m;
    float b51 = 2.f*lf*Caf/Iz;

    // preload ALL actions for this element: 25 float4 = 400 B. No interior
    // control flow in the main loop -> guaranteed full unroll -> abuf stays
    // in registers.
    const float4* ap = (const float4*)(actions + (size_t)e * 100);
    float4 abuf[25];
    #pragma unroll
    for (int j = 0; j < 25; ++j) abuf[j] = ap[j];

    // this thread's store base: subslot `sub` of element e's per-group chunk
    float* obase = out + (size_t)e * 400 + sub * 4;

    #pragma unroll
    for (int g = 0; g < 25; ++g) {          // 25 groups of 2 steps
        const float4 a4 = abuf[g];
        float4 o4[4];
        #pragma unroll
        for (int hh = 0; hh < 2; ++hh) {
            float psi = s4;
            float c  = __cosf(psi);
            float sn = __sinf(psi);
            float Vx  = c*s1 + sn*s3;
            float sb3 = c*s3 - sn*s1;
            float inv = __builtin_amdgcn_rcpf(Vx);
            float t3 = -k1*inv*sb3 + (-Vx - k2*inv)*s5 + b31*u1;
            float t5 = -k3*inv*sb3 - k4*inv*psi + b51*u1;
            float p0 = s0 + DT*(c*Vx - sn*sb3);
            float p2 = s2 + DT*(sn*Vx + c*sb3);
            float p1 = s1 + DT*(c*u0 - sn*t3);
            float p3 = s3 + DT*(sn*u0 + c*t3);
            float p4 = s4 + DT*s5;
            float p5 = s5 + DT*t5;
            float nu0 = hh ? a4.z : a4.x;
            float nu1 = hh ? a4.w : a4.y;
            o4[hh*2 + 0] = make_float4(p0, p1, p2, p3);
            o4[hh*2 + 1] = make_float4(p4, p5, nu0, nu1);
            s0=p0; s1=p1; s2=p2; s3=p3; s4=p4; s5=p5; u0=nu0; u1=nu1;
        }

        // compile-time-indexed select of this thread's subslot (cndmask tree,
        // NOT a runtime array index -- avoids scratch per rule #20), then one
        // dwordx4 store; the wave's 64 lanes cover 16 full 64B sectors.
        float4 v = (sub == 0) ? o4[0]
                 : (sub == 1) ? o4[1]
                 : (sub == 2) ? o4[2]
                 :              o4[3];
        *(float4*)(obase + g * 16) = v;
    }
}

extern "C" void kernel_launch(void* const* d_in, const int* in_sizes, int n_in,
                              void* d_out, int out_size, void* d_ws, size_t ws_size,
                              hipStream_t stream) {
    const float* fs      = (const float*)d_in[0]; // (B,1,8)
    const float* actions = (const float*)d_in[1]; // (B,50,2)
    int batch = in_sizes[0] / 8;                  // 131072
    int grid  = (batch * 4) / 256;                // 4 threads/element -> 2048 blocks
    hybrid_sim_kernel<<<grid, 256, 0, stream>>>(
        fs, actions,
        (const float*)d_in[2], (const float*)d_in[3], (const float*)d_in[4],
        (const float*)d_in[5], (const float*)d_in[6], (const float*)d_in[7],
        (float*)d_out);
}

// Round 4
// 302.383 us; speedup vs baseline: 1.3386x; 1.3386x over previous
//
#include <hip/hip_runtime.h>

#define DT 0.01f
// LDS element row: 4 groups x 4 float4 = 16 float4 data + 1 float4 pad = 17
// float4 (68 dwords, 272 B). 17 is odd => quad-bank index (byte/16 mod 8) of
// any b128 access at el*17+slot is (el+slot) mod 8:
//   stage  (lane=el, slot=4gs+j):        8 consecutive lanes -> 8 distinct quads
//   drain  (el=4k+(lane>>4), slot=lane&15): every 8-lane phase -> 8 distinct quads
// => all LDS traffic conflict-free.
#define ROWQ 17   // float4 per element row

// One thread per batch element; 50-step sequential scan in registers.
// vs the 302.7us round-0 version: drain is batched 4 groups at a time, so each
// element's store run is 256 B CONTIGUOUS (4 fully-dirty 128B L2 lines) instead
// of scattered 64 B chunks. Round-3 counters measured 1.41x write amplification
// (WRITE_SIZE 296 MB vs 209.7 ideal) from partial-line writebacks -- this is
// the targeted fix. Instruction count per group is unchanged vs round 2
// (4 stage + 4 read + 4 store); occupancy unchanged (69.6 KB LDS -> 2 blk/CU,
// grid-capped at 8 waves/CU either way). Full action preload, fully unrolled,
// no interior control flow (abuf must never be runtime-indexed), wave-private
// LDS quarters, zero barriers (intra-wave in-order DS pipe).
__global__ __launch_bounds__(256) void hybrid_sim_kernel(
    const float* __restrict__ fs,
    const float* __restrict__ actions,
    const float* __restrict__ pm,  const float* __restrict__ pCaf,
    const float* __restrict__ pCar, const float* __restrict__ plf,
    const float* __restrict__ plr, const float* __restrict__ pIz,
    float* __restrict__ out)
{
    __shared__ __align__(16) float lds[4 * 64 * (ROWQ*4)];   // 69.6 KB

    const int tid  = threadIdx.x;
    const int lane = tid & 63;
    const int wv   = tid >> 6;
    const int b    = blockIdx.x * 256 + tid;
    const int b0w  = blockIdx.x * 256 + (wv << 6);

    // initial state: full_states[b, 0, 0:8]
    const float4* fsp = (const float4*)(fs + (size_t)b * 8);
    float4 f0 = fsp[0];
    float4 f1 = fsp[1];
    float s0=f0.x, s1=f0.y, s2=f0.z, s3=f0.w, s4=f1.x, s5=f1.y, u0=f1.z, u1=f1.w;

    // wave-uniform coefficients
    float m=*pm, Caf=*pCaf, Car=*pCar, lf=*plf, lr=*plr, Iz=*pIz;
    float k1  = 2.f*(Caf+Car)/m;
    float k2  = 2.f*(Caf*lf-Car*lr)/m;
    float k3  = 2.f*(lf*Caf-lr*Car)/Iz;
    float k4  = 2.f*(lf*lf*Caf+lr*lr*Car)/Iz;
    float b31 = 2.f*Caf/m;
    float b51 = 2.f*lf*Caf/Iz;

    // preload ALL actions for this thread: 25 float4 = 400 B
    const float4* ap = (const float4*)(actions + (size_t)b * 100);
    float4 abuf[25];
    #pragma unroll
    for (int j = 0; j < 25; ++j) abuf[j] = ap[j];

    float* buf = &lds[wv * 64 * (ROWQ*4)];
    const int rq4 = lane >> 4;   // chunk drain: element subindex within 4-group
    const int rs  = lane & 15;   // chunk drain: float4 slot within 256B run

    float4 o4[4];

    #pragma unroll
    for (int c = 0; c < 6; ++c) {           // 6 chunks of 4 groups (g = 0..23)
        #pragma unroll
        for (int gs = 0; gs < 4; ++gs) {
            const float4 a4 = abuf[c*4 + gs];
            #pragma unroll
            for (int hh = 0; hh < 2; ++hh) {
                float psi = s4;
                float cc = __cosf(psi);
                float sn = __sinf(psi);
                float Vx  = cc*s1 + sn*s3;
                float sb3 = cc*s3 - sn*s1;
                float inv = __builtin_amdgcn_rcpf(Vx);
                float t3 = -k1*inv*sb3 + (-Vx - k2*inv)*s5 + b31*u1;
                float t5 = -k3*inv*sb3 - k4*inv*psi + b51*u1;
                float p0 = s0 + DT*(cc*Vx - sn*sb3);
                float p2 = s2 + DT*(sn*Vx + cc*sb3);
                float p1 = s1 + DT*(cc*u0 - sn*t3);
                float p3 = s3 + DT*(sn*u0 + cc*t3);
                float p4 = s4 + DT*s5;
                float p5 = s5 + DT*t5;
                float nu0 = hh ? a4.z : a4.x;
                float nu1 = hh ? a4.w : a4.y;
                o4[hh*2 + 0] = make_float4(p0, p1, p2, p3);
                o4[hh*2 + 1] = make_float4(p4, p5, nu0, nu1);
                s0=p0; s1=p1; s2=p2; s3=p3; s4=p4; s5=p5; u0=nu0; u1=nu1;
            }
            // stage group gs of this chunk: 4 x ds_write_b128, conflict-free
            #pragma unroll
            for (int j = 0; j < 4; ++j) {
                *(float4*)(buf + (lane*ROWQ + gs*4 + j) * 4) = o4[j];
            }
        }

        // drain chunk: 16 x (ds_read_b128 + global_store_dwordx4).
        // Each store instr: 4 elements x 256 B CONTIGUOUS run (16 lanes/run).
        #pragma unroll
        for (int k = 0; k < 16; ++k) {
            const int e = k*4 + rq4;
            float4 v = *(const float4*)(buf + (e*ROWQ + rs) * 4);
            *(float4*)(out + (size_t)(b0w + e)*400 + c*64 + rs*4) = v;
        }
    }

    // epilogue: group 24 alone (compute, stage, 64B-run drain like round 2)
    {
        const float4 a4 = abuf[24];
        #pragma unroll
        for (int hh = 0; hh < 2; ++hh) {
            float psi = s4;
            float cc = __cosf(psi);
            float sn = __sinf(psi);
            float Vx  = cc*s1 + sn*s3;
            float sb3 = cc*s3 - sn*s1;
            float inv = __builtin_amdgcn_rcpf(Vx);
            float t3 = -k1*inv*sb3 + (-Vx - k2*inv)*s5 + b31*u1;
            float t5 = -k3*inv*sb3 - k4*inv*psi + b51*u1;
            float p0 = s0 + DT*(cc*Vx - sn*sb3);
            float p2 = s2 + DT*(sn*Vx + cc*sb3);
            float p1 = s1 + DT*(cc*u0 - sn*t3);
            float p3 = s3 + DT*(sn*u0 + cc*t3);
            float p4 = s4 + DT*s5;
            float p5 = s5 + DT*t5;
            float nu0 = hh ? a4.z : a4.x;
            float nu1 = hh ? a4.w : a4.y;
            o4[hh*2 + 0] = make_float4(p0, p1, p2, p3);
            o4[hh*2 + 1] = make_float4(p4, p5, nu0, nu1);
            s0=p0; s1=p1; s2=p2; s3=p3; s4=p4; s5=p5; u0=nu0; u1=nu1;
        }
        #pragma unroll
        for (int j = 0; j < 4; ++j) {
            *(float4*)(buf + (lane*ROWQ + j) * 4) = o4[j];
        }
        const int rq = lane >> 2;
        const int rm = lane & 3;
        #pragma unroll
        for (int k = 0; k < 4; ++k) {
            const int e = k*16 + rq;
            float4 v = *(const float4*)(buf + (e*ROWQ + rm) * 4);
            *(float4*)(out + (size_t)(b0w + e)*400 + 24*16 + rm*4) = v;
        }
    }
}

extern "C" void kernel_launch(void* const* d_in, const int* in_sizes, int n_in,
                              void* d_out, int out_size, void* d_ws, size_t ws_size,
                              hipStream_t stream) {
    const float* fs      = (const float*)d_in[0]; // (B,1,8)
    const float* actions = (const float*)d_in[1]; // (B,50,2)
    int batch = in_sizes[0] / 8;                  // 131072, divisible by 256
    int grid  = batch / 256;
    hybrid_sim_kernel<<<grid, 256, 0, stream>>>(
        fs, actions,
        (const float*)d_in[2], (const float*)d_in[3], (const float*)d_in[4],
        (const float*)d_in[5], (const float*)d_in[6], (const float*)d_in[7],
        (float*)d_out);
}